// Round 2
// baseline (274.656 us; speedup 1.0000x reference)
//
#include <hip/hip_runtime.h>
#include <cstdint>
#include <cstddef>

// Problem constants
#define B_ 64
#define Q_ 16
#define A_ 4096
#define D_ 128
#define H_ 8
#define HD_ 16
#define FF_ 512
#define NCHUNK 8     // key-chunks per batch (A / 512)
#define CHUNK 512    // keys per block
// log2(e)/4  (folds softmax base-2 conversion and 1/sqrt(HD) into gq)
#define GQ_SCALE 0.36067376022224085f

typedef __attribute__((ext_vector_type(4))) float f32x4;
typedef __attribute__((ext_vector_type(8))) __bf16 bf16x8;
typedef __attribute__((ext_vector_type(4))) short s16x4;

static __device__ __forceinline__ short f2bf(float f) {
    __bf16 h = (__bf16)f;
    return __builtin_bit_cast(short, h);
}

static __device__ __forceinline__ f32x4 mfma32(bf16x8 a, bf16x8 b, f32x4 c) {
    return __builtin_amdgcn_mfma_f32_16x16x32_bf16(a, b, c, 0, 0, 0);
}

// Load 8 consecutive f32 from a weight row, convert to a bf16x8 MFMA fragment.
static __device__ __forceinline__ bf16x8 wfrag_load(const float* p) {
    float4 a = *(const float4*)p;
    float4 b = *(const float4*)(p + 4);
    bf16x8 r;
    r[0]=(__bf16)a.x; r[1]=(__bf16)a.y; r[2]=(__bf16)a.z; r[3]=(__bf16)a.w;
    r[4]=(__bf16)b.x; r[5]=(__bf16)b.y; r[6]=(__bf16)b.z; r[7]=(__bf16)b.w;
    return r;
}

// ---------------------------------------------------------------------------
// Kernel A: gq = LayerNorm(q) @ W_q.T, scaled by log2e/4, stored bf16.
// grid 1024 (= B*Q rows), block 128.
// ---------------------------------------------------------------------------
__global__ __launch_bounds__(128) void kgq(
    const float* __restrict__ qin, const float* __restrict__ g1,
    const float* __restrict__ b1, const float* __restrict__ Wq,
    short* __restrict__ gq)
{
    __shared__ float sx[128];
    __shared__ float red[2];
    int r = blockIdx.x;
    int t = threadIdx.x;
    float x = qin[(size_t)r * 128 + t];
    float v = x;
    for (int o = 32; o > 0; o >>= 1) v += __shfl_down(v, o);
    if ((t & 63) == 0) red[t >> 6] = v;
    __syncthreads();
    float mu = (red[0] + red[1]) * (1.f / 128.f);
    __syncthreads();
    float d = x - mu;
    v = d * d;
    for (int o = 32; o > 0; o >>= 1) v += __shfl_down(v, o);
    if ((t & 63) == 0) red[t >> 6] = v;
    __syncthreads();
    float var = (red[0] + red[1]) * (1.f / 128.f);
    float xn = d * rsqrtf(var + 1e-5f) * g1[t] + b1[t];
    sx[t] = xn;
    __syncthreads();
    float acc = 0.f;
    const float4* wr = (const float4*)(Wq + (size_t)t * 128);
    const float4* xv = (const float4*)sx;
    for (int i = 0; i < 32; ++i) {
        float4 a = wr[i], bb = xv[i];
        acc += a.x * bb.x + a.y * bb.y + a.z * bb.z + a.w * bb.w;
    }
    gq[(size_t)r * 128 + t] = f2bf(acc * GQ_SCALE);
}

// ---------------------------------------------------------------------------
// Kernel B: fused KV-projection + flash attention partials.
// grid (NCHUNK, B), block 256 (4 waves). Waves 0,1 compute K^T = W_k . emb^T,
// waves 2,3 compute V = emb . W_v^T; all 4 waves then do attention for 2 heads
// each. LDS fragment layouts are "fragment-major": writer D-reg quads are
// consecutive b64 stores, reader fragments are contiguous b128 loads.
// T14 async-stage: next subtile's global loads are issued right after the
// current subtile's LDS writes; in flight across KV-MFMA + attention phases.
// Partial (m, l, unnormalized ctx) per (b, h, chunk, q) goes to workspace.
// NOTE: the scores kB read intentionally over-reads past each 256-elem K^T
// region for lanes g>=2; those values multiply an explicitly-zeroed A half
// and the touched bytes (KR tail + VR head) are always valid bf16 written
// before the same barrier — harmless by construction.
// ---------------------------------------------------------------------------
__global__ __launch_bounds__(256, 2) void kattn(
    const float* __restrict__ embed, const int* __restrict__ bmask,
    const unsigned char* __restrict__ amask, const float* __restrict__ Wkv,
    const short* __restrict__ gq, float* __restrict__ pml,
    float* __restrict__ pctx)
{
    __shared__ __align__(16) short lds[32768];       // 64 KB
    const int KR  = 8192;     // 8192: K^T regions, (h,kb16): 256 elems, frag-major
    const int VR  = 16384;    // 8192: V regions, (h,kb32): 512 elems, frag-major
    const int PR  = 24576;    // 4096: per-wave P regions, 2 x 512 elems
    const int MK  = 28672;    // 4096 shorts = 8192 B: mask bytes [16][512]

    const int chunk = blockIdx.x;
    const int b     = blockIdx.y;
    const int t = threadIdx.x;
    const int w = t >> 6;          // wave id 0..3
    const int l = t & 63;
    const int g = l >> 4;          // 16-lane group 0..3
    const int c = l & 15;
    const int s = bmask[b];        // source batch
    const int a0 = chunk * CHUNK;

    // --- stage attn_mask chunk: 16 q-rows x 512 key bytes
    {
        unsigned char* mlb = (unsigned char*)&lds[MK];
        int qr = t >> 5, off = (t & 31) * 16;
        for (int p = 0; p < 2; ++p) {
            int qq = qr + p * 8;
            *(uint4*)&mlb[qq * 512 + off] =
                *(const uint4*)&amask[((size_t)(b * 16 + qq)) * 4096 + a0 + off];
        }
    }

    // --- loop-invariant weight fragments (k-waves: A-frags of W_k rows;
    //     v-waves: B-frags of W_v rows). 16 frags x 4 VGPR each.
    const bool kw = (w < 2);
    const int wrow0 = kw ? (w * 64) : (128 + (w - 2) * 64);
    bf16x8 wf[4][4];
    for (int xf = 0; xf < 4; ++xf)
        for (int kf = 0; kf < 4; ++kf)
            wf[xf][kf] = wfrag_load(Wkv + (size_t)(wrow0 + xf * 16 + c) * 128
                                        + kf * 32 + g * 8);

    // --- gq A-fragments for this wave's two heads (K=32 frag; kd>=16 zeroed
    //     so the padded half of the scores MFMA contributes exactly 0).
    bf16x8 gqA[2];
    for (int hh = 0; hh < 2; ++hh) {
        int h = 2 * w + hh;
        if (g < 2)
            gqA[hh] = *(const bf16x8*)(const void*)
                      (gq + ((size_t)(b * 16 + c)) * 128 + h * 16 + g * 8);
        else {
            bf16x8 z = {};
            gqA[hh] = z;
        }
    }

    f32x4 ctx[2];
    float mrun[2][4], lrun[2][4];
    for (int hh = 0; hh < 2; ++hh)
        for (int r = 0; r < 4; ++r) {
            ctx[hh][r] = 0.f; mrun[hh][r] = -3.0e38f; lrun[hh][r] = 0.f;
        }

    const float* esrc = embed + ((size_t)s * 4096 + a0) * 128;
    const int srow = t >> 5;             // staging row 0..7
    const int scol = (t & 31) * 4;       // staging f32 col

    float4 pf[8];                        // prefetch regs (one 64x128 subtile / block)
    auto loadregs = [&](int ts) {
        for (int p = 0; p < 8; ++p) {
            int rr = srow + p * 8;
            pf[p] = *(const float4*)(esrc + (size_t)(ts * 64 + rr) * 128 + scol);
        }
    };
    loadregs(0);

    for (int ts = 0; ts < 8; ++ts) {               // 8 subtiles of 64 keys
        __syncthreads();                           // prev iter's EMB readers done
        // --- write embed subtile [64 keys][128] bf16 LDS (XOR swizzle) from regs
        for (int p = 0; p < 8; ++p) {
            int rr = srow + p * 8;
            int byte = (rr * 256 + scol * 2) ^ ((rr & 7) << 4);
            s16x4 pk;
            pk[0] = f2bf(pf[p].x); pk[1] = f2bf(pf[p].y);
            pk[2] = f2bf(pf[p].z); pk[3] = f2bf(pf[p].w);
            *(s16x4*)(void*)((char*)lds + byte) = pk;
        }
        if (ts < 7) loadregs(ts + 1);              // T14: issue next loads now
        __syncthreads();
        // --- KV projection: 64 MFMAs/wave; results written frag-major (b64)
        for (int kb4 = 0; kb4 < 4; ++kb4) {        // 16-key blocks
            bf16x8 eb[4];
            for (int kf = 0; kf < 4; ++kf) {
                int rr = kb4 * 16 + c;
                int byte = (rr * 256 + kf * 64 + g * 16) ^ ((rr & 7) << 4);
                eb[kf] = *(const bf16x8*)(const void*)((char*)lds + byte);
            }
            for (int xf = 0; xf < 4; ++xf) {
                f32x4 acc = {0.f, 0.f, 0.f, 0.f};
                if (kw) { for (int kf = 0; kf < 4; ++kf) acc = mfma32(wf[xf][kf], eb[kf], acc); }
                else    { for (int kf = 0; kf < 4; ++kf) acc = mfma32(eb[kf], wf[xf][kf], acc); }
                s16x4 pk;
                pk[0] = f2bf(acc[0]); pk[1] = f2bf(acc[1]);
                pk[2] = f2bf(acc[2]); pk[3] = f2bf(acc[3]);
                if (kw) {
                    // K^T: D row = kd-local (4g+reg), col = key = c
                    int h = w * 4 + xf;
                    int e = (h * 4 + kb4) * 256 + (g >> 1) * 128 + c * 8 + (g & 1) * 4;
                    *(s16x4*)(void*)&lds[KR + e] = pk;
                } else {
                    // V: D row = key-local (4g+reg), col = vd = c
                    int h = (w - 2) * 4 + xf;
                    int e = (h * 2 + (kb4 >> 1)) * 512
                          + ((2 * (kb4 & 1) + (g >> 1)) * 16 + c) * 8 + (g & 1) * 4;
                    *(s16x4*)(void*)&lds[VR + e] = pk;
                }
            }
        }
        __syncthreads();
        // --- attention for this wave's 2 heads
        float mb[4][4];
        {
            const unsigned char* mlb = (const unsigned char*)&lds[MK];
            for (int kb = 0; kb < 4; ++kb)
                for (int r = 0; r < 4; ++r)
                    mb[kb][r] = mlb[(4 * g + r) * 512 + ts * 64 + kb * 16 + c]
                                ? -1.0e30f : 0.0f;
        }
        for (int hh = 0; hh < 2; ++hh) {
            int h = 2 * w + hh;
            f32x4 sc[4];
            for (int kb = 0; kb < 4; ++kb) {
                bf16x8 kB = *(const bf16x8*)(const void*)
                            &lds[KR + (h * 4 + kb) * 256 + (g * 16 + c) * 8];
                f32x4 z = {0.f, 0.f, 0.f, 0.f};
                sc[kb] = mfma32(gqA[hh], kB, z);   // D: row=q(4g+reg), col=key(c)
            }
            float al[4], rs[4];
            for (int r = 0; r < 4; ++r) {
                float s0 = sc[0][r] + mb[0][r], s1 = sc[1][r] + mb[1][r];
                float s2 = sc[2][r] + mb[2][r], s3 = sc[3][r] + mb[3][r];
                sc[0][r] = s0; sc[1][r] = s1; sc[2][r] = s2; sc[3][r] = s3;
                float tm = fmaxf(fmaxf(s0, s1), fmaxf(s2, s3));
                for (int o = 1; o < 16; o <<= 1) tm = fmaxf(tm, __shfl_xor(tm, o));
                float mn = fmaxf(mrun[hh][r], tm);
                al[r] = exp2f(mrun[hh][r] - mn);
                mrun[hh][r] = mn;
            }
            for (int r = 0; r < 4; ++r) {
                float p0 = exp2f(sc[0][r] - mrun[hh][r]);
                float p1 = exp2f(sc[1][r] - mrun[hh][r]);
                float p2 = exp2f(sc[2][r] - mrun[hh][r]);
                float p3 = exp2f(sc[3][r] - mrun[hh][r]);
                sc[0][r] = p0; sc[1][r] = p1; sc[2][r] = p2; sc[3][r] = p3;
                float qsum = p0 + p1 + p2 + p3;
                for (int o = 1; o < 16; o <<= 1) qsum += __shfl_xor(qsum, o);
                rs[r] = qsum;
            }
            for (int r = 0; r < 4; ++r) {
                lrun[hh][r] = lrun[hh][r] * al[r] + rs[r];
                ctx[hh][r] *= al[r];
            }
            // write P (bf16) frag-major; b16 scatter (writer holds q-quads)
            for (int kb = 0; kb < 4; ++kb) {
                int base = PR + w * 1024 + (kb >> 1) * 512;
                int khi = 2 * (kb & 1) + (c >> 3);
                for (int r = 0; r < 4; ++r)
                    lds[base + (khi * 16 + 4 * g + r) * 8 + (c & 7)] = f2bf(sc[kb][r]);
            }
            // PV: 2 MFMAs of K=32 keys
            for (int k2 = 0; k2 < 2; ++k2) {
                bf16x8 pA = *(const bf16x8*)(const void*)
                            &lds[PR + w * 1024 + k2 * 512 + (g * 16 + c) * 8];
                bf16x8 vB = *(const bf16x8*)(const void*)
                            &lds[VR + (h * 2 + k2) * 512 + (g * 16 + c) * 8];
                ctx[hh] = mfma32(pA, vB, ctx[hh]);
            }
        }
    }
    // --- epilogue: write per-chunk partials
    for (int hh = 0; hh < 2; ++hh) {
        int h = 2 * w + hh;
        size_t base = (((size_t)b * 8 + h) * 8 + chunk) * 16;
        for (int r = 0; r < 4; ++r)
            pctx[(base + 4 * g + r) * 16 + c] = ctx[hh][r];
        if (c == 0) {
            for (int r = 0; r < 4; ++r) {
                pml[(base + 4 * g + r) * 2 + 0] = mrun[hh][r];
                pml[(base + 4 * g + r) * 2 + 1] = lrun[hh][r];
            }
        }
    }
}

// ---------------------------------------------------------------------------
// Kernel C: combine chunk partials -> ctx, att_out = ctx @ W_o.T,
// hidden = q + a1*att_out, hn = LayerNorm2(hidden) (bf16).
// grid 1024 (= B*Q), block 128 (thread = output dim d).
// ---------------------------------------------------------------------------
__global__ __launch_bounds__(128) void kcomb(
    const float* __restrict__ pml, const float* __restrict__ pctx,
    const float* __restrict__ Wo, const float* __restrict__ qin,
    const float* __restrict__ alpha1, const float* __restrict__ g2,
    const float* __restrict__ b2, float* __restrict__ hidden,
    short* __restrict__ hn)
{
    __shared__ float scx[128];
    __shared__ float red[2];
    int r = blockIdx.x;
    int b = r >> 4, qq = r & 15;
    int d = threadIdx.x;
    int h = d >> 4, vd = d & 15;
    size_t mlb = (((size_t)b * 8 + h) * 8) * 32 + qq * 2;
    float M = -3.0e38f;
    for (int cc = 0; cc < 8; ++cc) M = fmaxf(M, pml[mlb + cc * 32]);
    float L = 0.f, cx = 0.f;
    for (int cc = 0; cc < 8; ++cc) {
        float mm = pml[mlb + cc * 32], ll = pml[mlb + cc * 32 + 1];
        float f = exp2f(mm - M);
        L += ll * f;
        cx += pctx[((((size_t)b * 8 + h) * 8 + cc) * 16 + qq) * 16 + vd] * f;
    }
    cx /= L;
    scx[d] = cx;
    __syncthreads();
    float ao = 0.f;
    const float4* wo = (const float4*)(Wo + (size_t)d * 128);
    const float4* xv = (const float4*)scx;
    for (int i = 0; i < 32; ++i) {
        float4 a = wo[i], bb = xv[i];
        ao += a.x * bb.x + a.y * bb.y + a.z * bb.z + a.w * bb.w;
    }
    float hid = qin[(size_t)r * 128 + d] + alpha1[0] * ao;
    hidden[(size_t)r * 128 + d] = hid;
    // LayerNorm2
    float v = hid;
    for (int o = 32; o > 0; o >>= 1) v += __shfl_down(v, o);
    if ((d & 63) == 0) red[d >> 6] = v;
    __syncthreads();
    float mu = (red[0] + red[1]) * (1.f / 128.f);
    __syncthreads();
    float dd = hid - mu;
    v = dd * dd;
    for (int o = 32; o > 0; o >>= 1) v += __shfl_down(v, o);
    if ((d & 63) == 0) red[d >> 6] = v;
    __syncthreads();
    float var = (red[0] + red[1]) * (1.f / 128.f);
    hn[(size_t)r * 128 + d] = f2bf(dd * rsqrtf(var + 1e-5f) * g2[d] + b2[d]);
}

// ---------------------------------------------------------------------------
// Kernel D1: FF with split-j partials. grid (b, jt) = 256 blocks, 256 thr.
// ab = hn @ w_ff.T + b_ff (MFMA), h = silu(a)*b, partial ffout = h @ w_ff_out.T
// ---------------------------------------------------------------------------
__global__ __launch_bounds__(256) void kff(
    const short* __restrict__ hn, const float* __restrict__ wff,
    const float* __restrict__ bff, const float* __restrict__ wffo,
    float* __restrict__ ffp)
{
    __shared__ float abm[2][16][132];
    __shared__ __align__(16) short hm[16 * 136];
    int b = blockIdx.x >> 2, jt = blockIdx.x & 3;
    int t = threadIdx.x, w = t >> 6, l = t & 63, g = l >> 4, c = l & 15;
    (void)l;
    bf16x8 ha[4];
    for (int kf = 0; kf < 4; ++kf)
        ha[kf] = *(const bf16x8*)(const void*)
                 (hn + ((size_t)b * 16 + c) * 128 + kf * 32 + g * 8);
    int isb = w >> 1, colb = (w & 1) * 64;
    for (int nf = 0; nf < 4; ++nf) {
        f32x4 acc = {0.f, 0.f, 0.f, 0.f};
        int lcol = colb + nf * 16 + c;
        int wrow = isb * 512 + jt * 128 + lcol;
        for (int kf = 0; kf < 4; ++kf) {
            bf16x8 wb = wfrag_load(wff + (size_t)wrow * 128 + kf * 32 + g * 8);
            acc = mfma32(ha[kf], wb, acc);
        }
        float bias = bff[wrow];
        for (int r = 0; r < 4; ++r) abm[isb][4 * g + r][lcol] = acc[r] + bias;
    }
    __syncthreads();
    for (int it = 0; it < 8; ++it) {
        int e = it * 256 + t, qq = e >> 7, jj = e & 127;
        float a = abm[0][qq][jj], bb = abm[1][qq][jj];
        float hv = a * bb / (1.f + __expf(-a));     // silu(a)*b
        hm[qq * 136 + jj] = f2bf(hv);
    }
    __syncthreads();
    bf16x8 hf[4];
    for (int kf = 0; kf < 4; ++kf)
        hf[kf] = *(const bf16x8*)(const void*)&hm[c * 136 + kf * 32 + g * 8];
    for (int nf = 0; nf < 2; ++nf) {
        f32x4 a2 = {0.f, 0.f, 0.f, 0.f};
        int dout = w * 32 + nf * 16 + c;
        for (int kf = 0; kf < 4; ++kf) {
            bf16x8 wb = wfrag_load(wffo + (size_t)dout * 512 + jt * 128
                                        + kf * 32 + g * 8);
            a2 = mfma32(hf[kf], wb, a2);
        }
        for (int r = 0; r < 4; ++r)
            ffp[((size_t)jt * 1024 + b * 16 + 4 * g + r) * 128 + dout] = a2[r];
    }
}

// ---------------------------------------------------------------------------
// Kernel D2: out = hidden + alpha2 * (sum_jt ffp + b_ff_out). grid 512 x 256.
// ---------------------------------------------------------------------------
__global__ __launch_bounds__(256) void kout(
    const float* __restrict__ hidden, const float* __restrict__ ffp,
    const float* __restrict__ bffo, const float* __restrict__ alpha2,
    float* __restrict__ out)
{
    int i = blockIdx.x * 256 + threadIdx.x;
    float f = ffp[i] + ffp[131072 + i] + ffp[262144 + i] + ffp[393216 + i]
            + bffo[i & 127];
    out[i] = hidden[i] + alpha2[0] * f;
}

// ---------------------------------------------------------------------------
extern "C" void kernel_launch(void* const* d_in, const int* in_sizes, int n_in,
                              void* d_out, int out_size, void* d_ws, size_t ws_size,
                              hipStream_t stream)
{
    (void)in_sizes; (void)n_in; (void)out_size; (void)ws_size;
    const float* qin   = (const float*)d_in[0];
    const float* embed = (const float*)d_in[1];
    const unsigned char* amask = (const unsigned char*)d_in[2];
    const int*   bmask = (const int*)d_in[3];
    const float* Wkv   = (const float*)d_in[4];
    const float* Wq    = (const float*)d_in[5];
    const float* Wo    = (const float*)d_in[6];
    const float* g1    = (const float*)d_in[7];
    const float* b1    = (const float*)d_in[8];
    const float* g2    = (const float*)d_in[9];
    const float* b2    = (const float*)d_in[10];
    const float* al1   = (const float*)d_in[11];
    const float* al2   = (const float*)d_in[12];
    const float* wff   = (const float*)d_in[13];
    const float* bff   = (const float*)d_in[14];
    const float* wffo  = (const float*)d_in[15];
    const float* bffo  = (const float*)d_in[16];
    float* out = (float*)d_out;

    char* ws = (char*)d_ws;
    short* gqb  = (short*)(ws + 0);         // 256 KB  bf16 gq (scaled)
    short* hnb  = (short*)(ws + 262144);    // 256 KB  bf16 LN2(hidden)
    float* hid  = (float*)(ws + 524288);    // 512 KB  hidden f32
    float* pml  = (float*)(ws + 1048576);   // 512 KB  partial (m,l)
    float* pctx = (float*)(ws + 1572864);   // 4 MB    partial ctx
    float* ffp  = (float*)(ws + 5767168);   // 2 MB    FF partials
    // total ws use: 7,864,320 bytes

    kgq  <<<dim3(1024),   dim3(128), 0, stream>>>(qin, g1, b1, Wq, gqb);
    kattn<<<dim3(8, 64),  dim3(256), 0, stream>>>(embed, bmask, amask, Wkv,
                                                  gqb, pml, pctx);
    kcomb<<<dim3(1024),   dim3(128), 0, stream>>>(pml, pctx, Wo, qin, al1,
                                                  g2, b2, hid, hnb);
    kff  <<<dim3(256),    dim3(256), 0, stream>>>(hnb, wff, bff, wffo, ffp);
    kout <<<dim3(512),    dim3(256), 0, stream>>>(hid, ffp, bffo, al2, out);
}

// Round 7
// 271.761 us; speedup vs baseline: 1.0107x; 1.0107x over previous
//
#include <hip/hip_runtime.h>
#include <cstdint>
#include <cstddef>

// Problem constants
#define B_ 64
#define Q_ 16
#define A_ 4096
#define D_ 128
#define H_ 8
#define HD_ 16
#define FF_ 512
// log2(e)/4  (folds softmax base-2 conversion and 1/sqrt(HD) into gq)
#define GQ_SCALE 0.36067376022224085f

typedef __attribute__((ext_vector_type(4))) float f32x4;
typedef __attribute__((ext_vector_type(8))) __bf16 bf16x8;
typedef __attribute__((ext_vector_type(4))) short s16x4;

static __device__ __forceinline__ short f2bf(float f) {
    __bf16 h = (__bf16)f;
    return __builtin_bit_cast(short, h);
}

static __device__ __forceinline__ f32x4 mfma32(bf16x8 a, bf16x8 b, f32x4 c) {
    return __builtin_amdgcn_mfma_f32_16x16x32_bf16(a, b, c, 0, 0, 0);
}

// ---------------------------------------------------------------------------
// Kernel P: convert weights f32 -> bf16 into workspace (same flat layouts).
// 245760 elems total, 4 per thread, 240 blocks x 256.
// ---------------------------------------------------------------------------
__global__ __launch_bounds__(256) void kprep(
    const float* __restrict__ wkv, const float* __restrict__ wo,
    const float* __restrict__ wff, const float* __restrict__ wffo,
    short* __restrict__ o_kv, short* __restrict__ o_wo,
    short* __restrict__ o_ff, short* __restrict__ o_ffo)
{
    int i = (blockIdx.x * 256 + threadIdx.x) * 4;
    const float* src; short* dst; int off;
    if (i < 32768)       { src = wkv;  dst = o_kv;  off = i; }
    else if (i < 49152)  { src = wo;   dst = o_wo;  off = i - 32768; }
    else if (i < 180224) { src = wff;  dst = o_ff;  off = i - 49152; }
    else                 { src = wffo; dst = o_ffo; off = i - 180224; }
    float4 v = *(const float4*)(src + off);
    s16x4 p;
    p[0] = f2bf(v.x); p[1] = f2bf(v.y); p[2] = f2bf(v.z); p[3] = f2bf(v.w);
    *(s16x4*)(dst + off) = p;
}

// ---------------------------------------------------------------------------
// Kernel A: gq = LayerNorm(q) @ W_q.T, scaled by log2e/4, stored bf16.
// grid 1024 (= B*Q rows), block 128.  (unchanged — verified passing)
// ---------------------------------------------------------------------------
__global__ __launch_bounds__(128) void kgq(
    const float* __restrict__ qin, const float* __restrict__ g1,
    const float* __restrict__ b1, const float* __restrict__ Wq,
    short* __restrict__ gq)
{
    __shared__ float sx[128];
    __shared__ float red[2];
    int r = blockIdx.x;
    int t = threadIdx.x;
    float x = qin[(size_t)r * 128 + t];
    float v = x;
    for (int o = 32; o > 0; o >>= 1) v += __shfl_down(v, o);
    if ((t & 63) == 0) red[t >> 6] = v;
    __syncthreads();
    float mu = (red[0] + red[1]) * (1.f / 128.f);
    __syncthreads();
    float d = x - mu;
    v = d * d;
    for (int o = 32; o > 0; o >>= 1) v += __shfl_down(v, o);
    if ((t & 63) == 0) red[t >> 6] = v;
    __syncthreads();
    float var = (red[0] + red[1]) * (1.f / 128.f);
    float xn = d * rsqrtf(var + 1e-5f) * g1[t] + b1[t];
    sx[t] = xn;
    __syncthreads();
    float acc = 0.f;
    const float4* wr = (const float4*)(Wq + (size_t)t * 128);
    const float4* xv = (const float4*)sx;
    for (int i = 0; i < 32; ++i) {
        float4 a = wr[i], bb = xv[i];
        acc += a.x * bb.x + a.y * bb.y + a.z * bb.z + a.w * bb.w;
    }
    gq[(size_t)r * 128 + t] = f2bf(acc * GQ_SCALE);
}

// ---------------------------------------------------------------------------
// Kernel B: fused KV-projection + flash attention partials.
// grid (8, B), block 512 (8 waves). Waves 0..3 compute K^T rows [w*32,w*32+32)
// (heads 2w, 2w+1); waves 4..7 compute V rows likewise. Each wave then does
// attention for exactly ONE head (h = w). Fragment-major LDS layouts
// (writer D-reg quads = packed b64 stores, reader fragments = b128 loads).
// T14 async-stage: next subtile's global loads issued right after the LDS
// writes, in flight across KV-MFMA + attention phases.
// NOTE: the scores kB read intentionally over-reads past each 256-elem K^T
// region for lanes g>=2; those values multiply an explicitly-zeroed A half
// and the touched bytes (KR tail / VR head) are always valid bf16 written
// before the same barrier — harmless by construction.
// ---------------------------------------------------------------------------
__global__ __launch_bounds__(512, 4) void kattn(
    const float* __restrict__ embed, const int* __restrict__ bmask,
    const unsigned char* __restrict__ amask, const short* __restrict__ wkv16,
    const short* __restrict__ gq, float* __restrict__ pml,
    float* __restrict__ pctx)
{
    __shared__ __align__(16) short lds[36864];       // 72 KB
    const int KR  = 8192;     // 8192 shorts: K^T regions (h,kb4): [kd>>3][key][kd&7]
    const int VR  = 16384;    // 8192: V regions (h,kb32): [key5>>3][vd][key5&7]
    const int PR  = 24576;    // 8192: per-wave P regions (1024 each)
    const int MK  = 32768;    // 4096 shorts = 8192 B: mask bytes [16][512]

    const int chunk = blockIdx.x;
    const int b     = blockIdx.y;
    const int t = threadIdx.x;
    const int w = t >> 6;          // wave id 0..7
    const int l = t & 63;
    const int g = l >> 4;          // 16-lane group 0..3
    const int c = l & 15;
    const int s = bmask[b];        // source batch
    const int a0 = chunk * 512;

    // --- stage attn_mask chunk: 16 q-rows x 512 key bytes (one pass)
    {
        unsigned char* mlb = (unsigned char*)&lds[MK];
        int qr = t >> 5, off = (t & 31) * 16;
        *(uint4*)&mlb[qr * 512 + off] =
            *(const uint4*)&amask[((size_t)(b * 16 + qr)) * 4096 + a0 + off];
    }

    // --- loop-invariant weight fragments (bf16, 2 xf x 4 kf per wave)
    const bool kw = (w < 4);
    const int wrow0 = kw ? (w * 32) : (128 + (w - 4) * 32);
    bf16x8 wf[2][4];
    for (int xf = 0; xf < 2; ++xf)
        for (int kf = 0; kf < 4; ++kf)
            wf[xf][kf] = *(const bf16x8*)(const void*)
                         (wkv16 + (size_t)(wrow0 + xf * 16 + c) * 128
                                + kf * 32 + g * 8);

    // --- gq A-fragment for this wave's head (kd>=16 zeroed)
    bf16x8 gqA;
    if (g < 2)
        gqA = *(const bf16x8*)(const void*)
              (gq + ((size_t)(b * 16 + c)) * 128 + w * 16 + g * 8);
    else { bf16x8 z = {}; gqA = z; }

    f32x4 ctx = {0.f, 0.f, 0.f, 0.f};
    float mrun[4], lrun[4];
    for (int r = 0; r < 4; ++r) { mrun[r] = -3.0e38f; lrun[r] = 0.f; }

    const float* esrc = embed + ((size_t)s * 4096 + a0) * 128;
    const int srow = t >> 5;             // staging row 0..15
    const int scol = (t & 31) * 4;       // staging f32 col

    float4 pf[4];                        // prefetch regs (T14 async-stage)
    auto loadregs = [&](int ts) {
        for (int p = 0; p < 4; ++p)
            pf[p] = *(const float4*)(esrc + (size_t)(ts * 64 + srow + p * 16) * 128
                                     + scol);
    };
    loadregs(0);

    for (int ts = 0; ts < 8; ++ts) {               // 8 subtiles of 64 keys
        __syncthreads();                           // prev attention reads done
        // --- write embed subtile [64][128] bf16 (XOR swizzle) from regs
        for (int p = 0; p < 4; ++p) {
            int rr = srow + p * 16;
            int byte = (rr * 256 + scol * 2) ^ ((rr & 7) << 4);
            s16x4 pk;
            pk[0] = f2bf(pf[p].x); pk[1] = f2bf(pf[p].y);
            pk[2] = f2bf(pf[p].z); pk[3] = f2bf(pf[p].w);
            *(s16x4*)(void*)((char*)lds + byte) = pk;
        }
        if (ts < 7) loadregs(ts + 1);              // issue next loads now
        __syncthreads();
        // --- KV projection: 32 MFMAs/wave; frag-major writes
        for (int kb4 = 0; kb4 < 4; ++kb4) {
            bf16x8 eb[4];
            for (int kf = 0; kf < 4; ++kf) {
                int rr = kb4 * 16 + c;
                int byte = (rr * 256 + kf * 64 + g * 16) ^ ((rr & 7) << 4);
                eb[kf] = *(const bf16x8*)(const void*)((char*)lds + byte);
            }
            for (int xf = 0; xf < 2; ++xf) {
                f32x4 acc = {0.f, 0.f, 0.f, 0.f};
                if (kw) { for (int kf = 0; kf < 4; ++kf) acc = mfma32(wf[xf][kf], eb[kf], acc); }
                else    { for (int kf = 0; kf < 4; ++kf) acc = mfma32(eb[kf], wf[xf][kf], acc); }
                s16x4 pk;
                pk[0] = f2bf(acc[0]); pk[1] = f2bf(acc[1]);
                pk[2] = f2bf(acc[2]); pk[3] = f2bf(acc[3]);
                if (kw) {
                    int h = 2 * w + xf;            // D row = kd-local, col = key
                    int e = (h * 4 + kb4) * 256 + (g >> 1) * 128 + c * 8 + (g & 1) * 4;
                    *(s16x4*)(void*)&lds[KR + e] = pk;
                } else {
                    int h = 2 * (w - 4) + xf;      // D row = key-local, col = vd
                    int e = (h * 2 + (kb4 >> 1)) * 512
                          + ((2 * (kb4 & 1) + (g >> 1)) * 16 + c) * 8 + (g & 1) * 4;
                    *(s16x4*)(void*)&lds[VR + e] = pk;
                }
            }
        }
        __syncthreads();
        // --- attention, head h = w
        float mb[4][4];
        {
            const unsigned char* mlb = (const unsigned char*)&lds[MK];
            for (int kb = 0; kb < 4; ++kb)
                for (int r = 0; r < 4; ++r)
                    mb[kb][r] = mlb[(4 * g + r) * 512 + ts * 64 + kb * 16 + c]
                                ? -1.0e30f : 0.0f;
        }
        f32x4 sc[4];
        for (int kb = 0; kb < 4; ++kb) {
            bf16x8 kB = *(const bf16x8*)(const void*)
                        &lds[KR + (w * 4 + kb) * 256 + (g * 16 + c) * 8];
            f32x4 z = {0.f, 0.f, 0.f, 0.f};
            sc[kb] = mfma32(gqA, kB, z);           // D: row=q(4g+r), col=key(c)
        }
        float al[4], rs[4];
        for (int r = 0; r < 4; ++r) {
            float s0 = sc[0][r] + mb[0][r], s1 = sc[1][r] + mb[1][r];
            float s2 = sc[2][r] + mb[2][r], s3 = sc[3][r] + mb[3][r];
            sc[0][r] = s0; sc[1][r] = s1; sc[2][r] = s2; sc[3][r] = s3;
            float tm = fmaxf(fmaxf(s0, s1), fmaxf(s2, s3));
            for (int o = 1; o < 16; o <<= 1) tm = fmaxf(tm, __shfl_xor(tm, o));
            float mn = fmaxf(mrun[r], tm);
            al[r] = exp2f(mrun[r] - mn);
            mrun[r] = mn;
        }
        for (int r = 0; r < 4; ++r) {
            float p0 = exp2f(sc[0][r] - mrun[r]);
            float p1 = exp2f(sc[1][r] - mrun[r]);
            float p2 = exp2f(sc[2][r] - mrun[r]);
            float p3 = exp2f(sc[3][r] - mrun[r]);
            sc[0][r] = p0; sc[1][r] = p1; sc[2][r] = p2; sc[3][r] = p3;
            float qsum = p0 + p1 + p2 + p3;
            for (int o = 1; o < 16; o <<= 1) qsum += __shfl_xor(qsum, o);
            rs[r] = qsum;
        }
        for (int r = 0; r < 4; ++r) {
            lrun[r] = lrun[r] * al[r] + rs[r];
            ctx[r] *= al[r];
        }
        // P write (bf16) frag-major
        for (int kb = 0; kb < 4; ++kb) {
            int base = PR + w * 1024 + (kb >> 1) * 512;
            int khi = 2 * (kb & 1) + (c >> 3);
            for (int r = 0; r < 4; ++r)
                lds[base + (khi * 16 + 4 * g + r) * 8 + (c & 7)] = f2bf(sc[kb][r]);
        }
        // PV: 2 MFMAs of K=32 keys
        for (int k2 = 0; k2 < 2; ++k2) {
            bf16x8 pA = *(const bf16x8*)(const void*)
                        &lds[PR + w * 1024 + k2 * 512 + (g * 16 + c) * 8];
            bf16x8 vB = *(const bf16x8*)(const void*)
                        &lds[VR + (w * 2 + k2) * 512 + (g * 16 + c) * 8];
            ctx = mfma32(pA, vB, ctx);
        }
    }
    // --- epilogue: per-chunk partials for head w
    size_t base = (((size_t)b * 8 + w) * 8 + chunk) * 16;
    for (int r = 0; r < 4; ++r)
        pctx[(base + 4 * g + r) * 16 + c] = ctx[r];
    if (c == 0) {
        for (int r = 0; r < 4; ++r) {
            pml[(base + 4 * g + r) * 2 + 0] = mrun[r];
            pml[(base + 4 * g + r) * 2 + 1] = lrun[r];
        }
    }
}

// ---------------------------------------------------------------------------
// Kernel T: fused tail. One block per batch b (64 blocks x 256 thr, 4 waves).
// combine partials -> ctx(bf16) -> att_out=ctx@Wo^T (MFMA) -> hidden ->
// LN2 -> ab=hn@wff^T (MFMA, a/b paired, silu in-reg, 8 nf = FULL 512 rows) ->
// ffout=h@wffo^T (MFMA) -> out = hidden + a2*(ffout+bffo).
// ---------------------------------------------------------------------------
__global__ __launch_bounds__(256, 2) void ktail(
    const float* __restrict__ pml, const float* __restrict__ pctx,
    const short* __restrict__ wo16, const float* __restrict__ qin,
    const float* __restrict__ alpha1, const float* __restrict__ g2,
    const float* __restrict__ b2, const short* __restrict__ wff16,
    const float* __restrict__ bff, const short* __restrict__ wffo16,
    const float* __restrict__ bffo, const float* __restrict__ alpha2,
    float* __restrict__ out)
{
    __shared__ __align__(16) short sctx[2048];   // ctx frag-major [d>>3][q][d&7]
    __shared__ __align__(16) float shid[2048];   // hidden [16][128]
    __shared__ __align__(16) short shn[2048];    // hn frag-major
    __shared__ __align__(16) short shm[8192];    // h frag-major [k>>3][q][k&7]
    const int b = blockIdx.x;
    const int t = threadIdx.x;
    const int w = t >> 6, l = t & 63, g = l >> 4, c = l & 15;
    (void)l;

    // --- phase 1: combine chunk partials -> normalized ctx (bf16, frag-major)
    {
        int hq = t >> 1, vh = t & 1;
        int h = hq >> 4, qq = hq & 15;
        const float* pm = pml + (((size_t)b * 8 + h) * 8) * 32 + qq * 2;
        float M = -3.0e38f;
        for (int cc = 0; cc < 8; ++cc) M = fmaxf(M, pm[cc * 32]);
        float L = 0.f;
        float cx[8] = {0.f,0.f,0.f,0.f,0.f,0.f,0.f,0.f};
        for (int cc = 0; cc < 8; ++cc) {
            float f = exp2f(pm[cc * 32] - M);
            L += pm[cc * 32 + 1] * f;
            const float* pc = pctx + ((((size_t)b * 8 + h) * 8 + cc) * 16 + qq) * 16
                            + vh * 8;
            for (int j = 0; j < 8; ++j) cx[j] += pc[j] * f;
        }
        float inv = 1.f / L;
        s16x4 p0, p1;
        for (int j = 0; j < 4; ++j) p0[j] = f2bf(cx[j] * inv);
        for (int j = 0; j < 4; ++j) p1[j] = f2bf(cx[4 + j] * inv);
        int off = (h * 2 + vh) * 128 + qq * 8;
        *(s16x4*)&sctx[off] = p0;
        *(s16x4*)&sctx[off + 4] = p1;
    }
    __syncthreads();
    // --- phase 2: att_out = ctx @ Wo^T; hidden = q + a1*att_out (to LDS)
    {
        float a1 = alpha1[0];
        bf16x8 cA[4];
        for (int kf = 0; kf < 4; ++kf)
            cA[kf] = *(const bf16x8*)(const void*)&sctx[(kf * 4 + g) * 128 + c * 8];
        for (int nf = 0; nf < 2; ++nf) {
            int dcol = w * 32 + nf * 16 + c;
            f32x4 acc = {0.f, 0.f, 0.f, 0.f};
            for (int kf = 0; kf < 4; ++kf) {
                bf16x8 wB = *(const bf16x8*)(const void*)
                            (wo16 + (size_t)dcol * 128 + kf * 32 + g * 8);
                acc = mfma32(cA[kf], wB, acc);
            }
            for (int r = 0; r < 4; ++r) {
                int q = 4 * g + r;
                float hid = qin[((size_t)b * 16 + q) * 128 + dcol] + a1 * acc[r];
                shid[q * 128 + dcol] = hid;
            }
        }
    }
    __syncthreads();
    // --- phase 3: LN2 per q-row -> shn (bf16, frag-major)
    {
        int row = t >> 4, ln = t & 15;
        float x[8], sum = 0.f, sq = 0.f;
        for (int j = 0; j < 8; ++j) {
            x[j] = shid[row * 128 + ln * 8 + j];
            sum += x[j]; sq += x[j] * x[j];
        }
        for (int o = 1; o < 16; o <<= 1) {
            sum += __shfl_xor(sum, o);
            sq  += __shfl_xor(sq, o);
        }
        float mu = sum * (1.f / 128.f);
        float var = sq * (1.f / 128.f) - mu * mu;
        float rstd = rsqrtf(var + 1e-5f);
        s16x4 h0, h1;
        for (int j = 0; j < 4; ++j)
            h0[j] = f2bf((x[j] - mu) * rstd * g2[ln * 8 + j] + b2[ln * 8 + j]);
        for (int j = 0; j < 4; ++j)
            h1[j] = f2bf((x[4 + j] - mu) * rstd * g2[ln * 8 + 4 + j] + b2[ln * 8 + 4 + j]);
        int off = ln * 128 + row * 8;
        *(s16x4*)&shn[off] = h0;
        *(s16x4*)&shn[off + 4] = h1;
    }
    __syncthreads();
    // --- phase 4: ab = hn @ wff^T + bias; h = silu(a)*b -> shm (frag-major)
    //     8 nf x 4 waves x 16 rows = FULL 512 gate rows (fixed from 256).
    {
        bf16x8 hA[4];
        for (int kf = 0; kf < 4; ++kf)
            hA[kf] = *(const bf16x8*)(const void*)&shn[(kf * 4 + g) * 128 + c * 8];
        for (int nf = 0; nf < 8; ++nf) {
            int arow = w * 128 + nf * 16 + c;
            int brow = 512 + arow;
            f32x4 aa = {0.f,0.f,0.f,0.f}, ab = {0.f,0.f,0.f,0.f};
            for (int kf = 0; kf < 4; ++kf) {
                bf16x8 wa = *(const bf16x8*)(const void*)
                            (wff16 + (size_t)arow * 128 + kf * 32 + g * 8);
                bf16x8 wb = *(const bf16x8*)(const void*)
                            (wff16 + (size_t)brow * 128 + kf * 32 + g * 8);
                aa = mfma32(hA[kf], wa, aa);
                ab = mfma32(hA[kf], wb, ab);
            }
            float ba = bff[arow], bb2 = bff[brow];
            for (int r = 0; r < 4; ++r) {
                float a = aa[r] + ba, bb = ab[r] + bb2;
                float hv = a * bb / (1.f + __expf(-a));   // silu(a)*b
                shm[(arow >> 3) * 128 + (4 * g + r) * 8 + (c & 7)] = f2bf(hv);
            }
        }
    }
    __syncthreads();
    // --- phase 5: ffout = h @ wffo^T; out = hidden + a2*(ffout + bffo)
    {
        float a2 = alpha2[0];
        for (int nf = 0; nf < 2; ++nf) {
            int dcol = w * 32 + nf * 16 + c;
            f32x4 acc = {0.f, 0.f, 0.f, 0.f};
            for (int kf = 0; kf < 16; ++kf) {
                bf16x8 hA = *(const bf16x8*)(const void*)
                            &shm[(kf * 4 + g) * 128 + c * 8];
                bf16x8 wB = *(const bf16x8*)(const void*)
                            (wffo16 + (size_t)dcol * 512 + kf * 32 + g * 8);
                acc = mfma32(hA, wB, acc);
            }
            float bo = bffo[dcol];
            for (int r = 0; r < 4; ++r) {
                int q = 4 * g + r;
                out[((size_t)b * 16 + q) * 128 + dcol] =
                    shid[q * 128 + dcol] + a2 * (acc[r] + bo);
            }
        }
    }
}

// ---------------------------------------------------------------------------
extern "C" void kernel_launch(void* const* d_in, const int* in_sizes, int n_in,
                              void* d_out, int out_size, void* d_ws, size_t ws_size,
                              hipStream_t stream)
{
    (void)in_sizes; (void)n_in; (void)out_size; (void)ws_size;
    const float* qin   = (const float*)d_in[0];
    const float* embed = (const float*)d_in[1];
    const unsigned char* amask = (const unsigned char*)d_in[2];
    const int*   bmask = (const int*)d_in[3];
    const float* Wkv   = (const float*)d_in[4];
    const float* Wq    = (const float*)d_in[5];
    const float* Wo    = (const float*)d_in[6];
    const float* g1    = (const float*)d_in[7];
    const float* b1    = (const float*)d_in[8];
    const float* g2    = (const float*)d_in[9];
    const float* b2    = (const float*)d_in[10];
    const float* al1   = (const float*)d_in[11];
    const float* al2   = (const float*)d_in[12];
    const float* wff   = (const float*)d_in[13];
    const float* bff   = (const float*)d_in[14];
    const float* wffo  = (const float*)d_in[15];
    const float* bffo  = (const float*)d_in[16];
    float* out = (float*)d_out;

    char* ws = (char*)d_ws;
    short* gqb    = (short*)(ws + 0);         // 256 KB bf16 gq (scaled)
    float* pml    = (float*)(ws + 262144);    // 512 KB partial (m,l)
    float* pctx   = (float*)(ws + 786432);    // 4 MB   partial ctx
    short* wkv16  = (short*)(ws + 4980736);   // 64 KB
    short* wo16   = (short*)(ws + 5046272);   // 32 KB
    short* wff16  = (short*)(ws + 5079040);   // 256 KB
    short* wffo16 = (short*)(ws + 5341184);   // 128 KB
    // total ws use: 5,472,256 bytes

    kprep<<<dim3(240),   dim3(256), 0, stream>>>(Wkv, Wo, wff, wffo,
                                                 wkv16, wo16, wff16, wffo16);
    kgq  <<<dim3(1024),  dim3(128), 0, stream>>>(qin, g1, b1, Wq, gqb);
    kattn<<<dim3(8, 64), dim3(512), 0, stream>>>(embed, bmask, amask, wkv16,
                                                 gqb, pml, pctx);
    ktail<<<dim3(64),    dim3(256), 0, stream>>>(pml, pctx, wo16, qin, al1,
                                                 g2, b2, wff16, bff, wffo16,
                                                 bffo, al2, out);
}

// Round 9
// 271.705 us; speedup vs baseline: 1.0109x; 1.0002x over previous
//
#include <hip/hip_runtime.h>
#include <cstdint>
#include <cstddef>

// Problem constants
#define B_ 64
#define Q_ 16
#define A_ 4096
#define D_ 128
#define H_ 8
#define HD_ 16
#define FF_ 512
// log2(e)/4  (folds softmax base-2 conversion and 1/sqrt(HD) into gq)
#define GQ_SCALE 0.36067376022224085f

typedef __attribute__((ext_vector_type(4))) float f32x4;
typedef __attribute__((ext_vector_type(8))) __bf16 bf16x8;
typedef __attribute__((ext_vector_type(4))) short s16x4;

static __device__ __forceinline__ short f2bf(float f) {
    __bf16 h = (__bf16)f;
    return __builtin_bit_cast(short, h);
}

static __device__ __forceinline__ f32x4 mfma32(bf16x8 a, bf16x8 b, f32x4 c) {
    return __builtin_amdgcn_mfma_f32_16x16x32_bf16(a, b, c, 0, 0, 0);
}

// ---------------------------------------------------------------------------
// Kernel P: convert weights f32 -> bf16 into workspace (same flat layouts).
// 245760 elems total, 4 per thread, 240 blocks x 256.
// ---------------------------------------------------------------------------
__global__ __launch_bounds__(256) void kprep(
    const float* __restrict__ wkv, const float* __restrict__ wo,
    const float* __restrict__ wff, const float* __restrict__ wffo,
    short* __restrict__ o_kv, short* __restrict__ o_wo,
    short* __restrict__ o_ff, short* __restrict__ o_ffo)
{
    int i = (blockIdx.x * 256 + threadIdx.x) * 4;
    const float* src; short* dst; int off;
    if (i < 32768)       { src = wkv;  dst = o_kv;  off = i; }
    else if (i < 49152)  { src = wo;   dst = o_wo;  off = i - 32768; }
    else if (i < 180224) { src = wff;  dst = o_ff;  off = i - 49152; }
    else                 { src = wffo; dst = o_ffo; off = i - 180224; }
    float4 v = *(const float4*)(src + off);
    s16x4 p;
    p[0] = f2bf(v.x); p[1] = f2bf(v.y); p[2] = f2bf(v.z); p[3] = f2bf(v.w);
    *(s16x4*)(dst + off) = p;
}

// ---------------------------------------------------------------------------
// Kernel A: gq = LayerNorm(q) @ W_q.T, scaled by log2e/4, stored bf16.
// grid 1024 (= B*Q rows), block 128.  (unchanged — verified passing)
// ---------------------------------------------------------------------------
__global__ __launch_bounds__(128) void kgq(
    const float* __restrict__ qin, const float* __restrict__ g1,
    const float* __restrict__ b1, const float* __restrict__ Wq,
    short* __restrict__ gq)
{
    __shared__ float sx[128];
    __shared__ float red[2];
    int r = blockIdx.x;
    int t = threadIdx.x;
    float x = qin[(size_t)r * 128 + t];
    float v = x;
    for (int o = 32; o > 0; o >>= 1) v += __shfl_down(v, o);
    if ((t & 63) == 0) red[t >> 6] = v;
    __syncthreads();
    float mu = (red[0] + red[1]) * (1.f / 128.f);
    __syncthreads();
    float d = x - mu;
    v = d * d;
    for (int o = 32; o > 0; o >>= 1) v += __shfl_down(v, o);
    if ((t & 63) == 0) red[t >> 6] = v;
    __syncthreads();
    float var = (red[0] + red[1]) * (1.f / 128.f);
    float xn = d * rsqrtf(var + 1e-5f) * g1[t] + b1[t];
    sx[t] = xn;
    __syncthreads();
    float acc = 0.f;
    const float4* wr = (const float4*)(Wq + (size_t)t * 128);
    const float4* xv = (const float4*)sx;
    for (int i = 0; i < 32; ++i) {
        float4 a = wr[i], bb = xv[i];
        acc += a.x * bb.x + a.y * bb.y + a.z * bb.z + a.w * bb.w;
    }
    gq[(size_t)r * 128 + t] = f2bf(acc * GQ_SCALE);
}

// ---------------------------------------------------------------------------
// Kernel B: fused KV-projection + flash attention partials.
// grid (8, B), block 512 (8 waves). Waves 0..3 compute K^T rows [w*32,w*32+32)
// (heads 2w, 2w+1); waves 4..7 compute V rows likewise. Each wave then does
// attention for exactly ONE head (h = w). Fragment-major LDS layouts
// (writer D-reg quads = packed b64 stores, reader fragments = b128 loads).
// T14 async-stage: next subtile's global loads issued right after the LDS
// writes, in flight across KV-MFMA + attention phases.
// Mask fast-path: one uint4 probe per lane + wave-uniform __any branch
// replaces 16 ds_read_u8 when the subtile's mask is all-zero (bench case).
// NOTE: the scores kB read intentionally over-reads past each 256-elem K^T
// region for lanes g>=2; those values multiply an explicitly-zeroed A half
// and the touched bytes (KR tail / VR head) are always valid bf16 written
// before the same barrier — harmless by construction.
// ---------------------------------------------------------------------------
__global__ __launch_bounds__(512, 4) void kattn(
    const float* __restrict__ embed, const int* __restrict__ bmask,
    const unsigned char* __restrict__ amask, const short* __restrict__ wkv16,
    const short* __restrict__ gq, float* __restrict__ pml,
    float* __restrict__ pctx)
{
    __shared__ __align__(16) short lds[36864];       // 72 KB
    const int KR  = 8192;     // 8192 shorts: K^T regions (h,kb4): [kd>>3][key][kd&7]
    const int VR  = 16384;    // 8192: V regions (h,kb32): [key5>>3][vd][key5&7]
    const int PR  = 24576;    // 8192: per-wave P regions (1024 each)
    const int MK  = 32768;    // 4096 shorts = 8192 B: mask bytes [16][512]

    const int chunk = blockIdx.x;
    const int b     = blockIdx.y;
    const int t = threadIdx.x;
    const int w = t >> 6;          // wave id 0..7
    const int l = t & 63;
    const int g = l >> 4;          // 16-lane group 0..3
    const int c = l & 15;
    const int s = bmask[b];        // source batch
    const int a0 = chunk * 512;

    // --- stage attn_mask chunk: 16 q-rows x 512 key bytes (one pass)
    {
        unsigned char* mlb = (unsigned char*)&lds[MK];
        int qr = t >> 5, off = (t & 31) * 16;
        *(uint4*)&mlb[qr * 512 + off] =
            *(const uint4*)&amask[((size_t)(b * 16 + qr)) * 4096 + a0 + off];
    }

    // --- loop-invariant weight fragments (bf16, 2 xf x 4 kf per wave)
    const bool kw = (w < 4);
    const int wrow0 = kw ? (w * 32) : (128 + (w - 4) * 32);
    bf16x8 wf[2][4];
    for (int xf = 0; xf < 2; ++xf)
        for (int kf = 0; kf < 4; ++kf)
            wf[xf][kf] = *(const bf16x8*)(const void*)
                         (wkv16 + (size_t)(wrow0 + xf * 16 + c) * 128
                                + kf * 32 + g * 8);

    // --- gq A-fragment for this wave's head (kd>=16 zeroed)
    bf16x8 gqA;
    if (g < 2)
        gqA = *(const bf16x8*)(const void*)
              (gq + ((size_t)(b * 16 + c)) * 128 + w * 16 + g * 8);
    else { bf16x8 z = {}; gqA = z; }

    f32x4 ctx = {0.f, 0.f, 0.f, 0.f};
    float mrun[4], lrun[4];
    for (int r = 0; r < 4; ++r) { mrun[r] = -3.0e38f; lrun[r] = 0.f; }

    const float* esrc = embed + ((size_t)s * 4096 + a0) * 128;
    const int srow = t >> 5;             // staging row 0..15
    const int scol = (t & 31) * 4;       // staging f32 col

    float4 pf[4];                        // prefetch regs (T14 async-stage)
    auto loadregs = [&](int ts) {
        for (int p = 0; p < 4; ++p)
            pf[p] = *(const float4*)(esrc + (size_t)(ts * 64 + srow + p * 16) * 128
                                     + scol);
    };
    loadregs(0);

    for (int ts = 0; ts < 8; ++ts) {               // 8 subtiles of 64 keys
        __syncthreads();                           // prev attention reads done
        // --- write embed subtile [64][128] bf16 (XOR swizzle) from regs
        for (int p = 0; p < 4; ++p) {
            int rr = srow + p * 16;
            int byte = (rr * 256 + scol * 2) ^ ((rr & 7) << 4);
            s16x4 pk;
            pk[0] = f2bf(pf[p].x); pk[1] = f2bf(pf[p].y);
            pk[2] = f2bf(pf[p].z); pk[3] = f2bf(pf[p].w);
            *(s16x4*)(void*)((char*)lds + byte) = pk;
        }
        if (ts < 7) loadregs(ts + 1);              // issue next loads now
        __syncthreads();
        // --- KV projection: 32 MFMAs/wave; frag-major writes
        for (int kb4 = 0; kb4 < 4; ++kb4) {
            bf16x8 eb[4];
            for (int kf = 0; kf < 4; ++kf) {
                int rr = kb4 * 16 + c;
                int byte = (rr * 256 + kf * 64 + g * 16) ^ ((rr & 7) << 4);
                eb[kf] = *(const bf16x8*)(const void*)((char*)lds + byte);
            }
            for (int xf = 0; xf < 2; ++xf) {
                f32x4 acc = {0.f, 0.f, 0.f, 0.f};
                if (kw) { for (int kf = 0; kf < 4; ++kf) acc = mfma32(wf[xf][kf], eb[kf], acc); }
                else    { for (int kf = 0; kf < 4; ++kf) acc = mfma32(eb[kf], wf[xf][kf], acc); }
                s16x4 pk;
                pk[0] = f2bf(acc[0]); pk[1] = f2bf(acc[1]);
                pk[2] = f2bf(acc[2]); pk[3] = f2bf(acc[3]);
                if (kw) {
                    int h = 2 * w + xf;            // D row = kd-local, col = key
                    int e = (h * 4 + kb4) * 256 + (g >> 1) * 128 + c * 8 + (g & 1) * 4;
                    *(s16x4*)(void*)&lds[KR + e] = pk;
                } else {
                    int h = 2 * (w - 4) + xf;      // D row = key-local, col = vd
                    int e = (h * 2 + (kb4 >> 1)) * 512
                          + ((2 * (kb4 & 1) + (g >> 1)) * 16 + c) * 8 + (g & 1) * 4;
                    *(s16x4*)(void*)&lds[VR + e] = pk;
                }
            }
        }
        __syncthreads();
        // --- attention, head h = w
        const unsigned char* mlb = (const unsigned char*)&lds[MK];
        float mb[4][4];
        // fast probe: 64 lanes cover 16 rows x 64 bytes of this subtile's mask
        {
            uint4 mchk = *(const uint4*)
                         &mlb[(4 * g + (c & 3)) * 512 + ts * 64 + (c >> 2) * 16];
            int any = (mchk.x | mchk.y | mchk.z | mchk.w) != 0;
            if (__any(any)) {
                for (int kb = 0; kb < 4; ++kb)
                    for (int r = 0; r < 4; ++r)
                        mb[kb][r] = mlb[(4 * g + r) * 512 + ts * 64 + kb * 16 + c]
                                    ? -1.0e30f : 0.0f;
            } else {
                for (int kb = 0; kb < 4; ++kb)
                    for (int r = 0; r < 4; ++r) mb[kb][r] = 0.0f;
            }
        }
        f32x4 sc[4];
        for (int kb = 0; kb < 4; ++kb) {
            bf16x8 kB = *(const bf16x8*)(const void*)
                        &lds[KR + (w * 4 + kb) * 256 + (g * 16 + c) * 8];
            f32x4 z = {0.f, 0.f, 0.f, 0.f};
            sc[kb] = mfma32(gqA, kB, z);           // D: row=q(4g+r), col=key(c)
        }
        float al[4], rs[4];
        for (int r = 0; r < 4; ++r) {
            float s0 = sc[0][r] + mb[0][r], s1 = sc[1][r] + mb[1][r];
            float s2 = sc[2][r] + mb[2][r], s3 = sc[3][r] + mb[3][r];
            sc[0][r] = s0; sc[1][r] = s1; sc[2][r] = s2; sc[3][r] = s3;
            float tm = fmaxf(fmaxf(s0, s1), fmaxf(s2, s3));
            for (int o = 1; o < 16; o <<= 1) tm = fmaxf(tm, __shfl_xor(tm, o));
            float mn = fmaxf(mrun[r], tm);
            al[r] = exp2f(mrun[r] - mn);
            mrun[r] = mn;
        }
        for (int r = 0; r < 4; ++r) {
            float p0 = exp2f(sc[0][r] - mrun[r]);
            float p1 = exp2f(sc[1][r] - mrun[r]);
            float p2 = exp2f(sc[2][r] - mrun[r]);
            float p3 = exp2f(sc[3][r] - mrun[r]);
            sc[0][r] = p0; sc[1][r] = p1; sc[2][r] = p2; sc[3][r] = p3;
            float qsum = p0 + p1 + p2 + p3;
            for (int o = 1; o < 16; o <<= 1) qsum += __shfl_xor(qsum, o);
            rs[r] = qsum;
        }
        for (int r = 0; r < 4; ++r) {
            lrun[r] = lrun[r] * al[r] + rs[r];
            ctx[r] *= al[r];
        }
        // P write (bf16) frag-major
        for (int kb = 0; kb < 4; ++kb) {
            int base = PR + w * 1024 + (kb >> 1) * 512;
            int khi = 2 * (kb & 1) + (c >> 3);
            for (int r = 0; r < 4; ++r)
                lds[base + (khi * 16 + 4 * g + r) * 8 + (c & 7)] = f2bf(sc[kb][r]);
        }
        // PV: 2 MFMAs of K=32 keys
        for (int k2 = 0; k2 < 2; ++k2) {
            bf16x8 pA = *(const bf16x8*)(const void*)
                        &lds[PR + w * 1024 + k2 * 512 + (g * 16 + c) * 8];
            bf16x8 vB = *(const bf16x8*)(const void*)
                        &lds[VR + (w * 2 + k2) * 512 + (g * 16 + c) * 8];
            ctx = mfma32(pA, vB, ctx);
        }
    }
    // --- epilogue: per-chunk partials for head w
    size_t base = (((size_t)b * 8 + w) * 8 + chunk) * 16;
    for (int r = 0; r < 4; ++r)
        pctx[(base + 4 * g + r) * 16 + c] = ctx[r];
    if (c == 0) {
        for (int r = 0; r < 4; ++r) {
            pml[(base + 4 * g + r) * 2 + 0] = mrun[r];
            pml[(base + 4 * g + r) * 2 + 1] = lrun[r];
        }
    }
}

// ---------------------------------------------------------------------------
// Kernel T: fused tail. One block per batch b, now 512 thr (8 waves) —
// halves per-wave serial work vs the 4-wave version, 2 waves/SIMD.
// combine partials -> ctx(bf16) -> att_out=ctx@Wo^T (MFMA) -> hidden ->
// LN2 -> ab=hn@wff^T (MFMA, a/b paired, silu in-reg, full 512 rows) ->
// ffout=h@wffo^T (MFMA) -> out = hidden + a2*(ffout+bffo).
// ---------------------------------------------------------------------------
__global__ __launch_bounds__(512, 2) void ktail(
    const float* __restrict__ pml, const float* __restrict__ pctx,
    const short* __restrict__ wo16, const float* __restrict__ qin,
    const float* __restrict__ alpha1, const float* __restrict__ g2,
    const float* __restrict__ b2, const short* __restrict__ wff16,
    const float* __restrict__ bff, const short* __restrict__ wffo16,
    const float* __restrict__ bffo, const float* __restrict__ alpha2,
    float* __restrict__ out)
{
    __shared__ __align__(16) short sctx[2048];   // ctx frag-major [d>>3][q][d&7]
    __shared__ __align__(16) float shid[2048];   // hidden [16][128]
    __shared__ __align__(16) short shn[2048];    // hn frag-major
    __shared__ __align__(16) short shm[8192];    // h frag-major [k>>3][q][k&7]
    const int b = blockIdx.x;
    const int t = threadIdx.x;                   // 0..511
    const int w = t >> 6, l = t & 63, g = l >> 4, c = l & 15;
    (void)l;

    // --- phase 1: combine chunk partials -> normalized ctx (bf16, frag-major)
    //     512 threads: (h,qq) = t>>2, each thread 4 vd elems (vh = t&3).
    {
        int hq = t >> 2, vh = t & 3;
        int h = hq >> 4, qq = hq & 15;
        const float* pm = pml + (((size_t)b * 8 + h) * 8) * 32 + qq * 2;
        float M = -3.0e38f;
        for (int cc = 0; cc < 8; ++cc) M = fmaxf(M, pm[cc * 32]);
        float L = 0.f;
        float cx[4] = {0.f, 0.f, 0.f, 0.f};
        for (int cc = 0; cc < 8; ++cc) {
            float f = exp2f(pm[cc * 32] - M);
            L += pm[cc * 32 + 1] * f;
            const float* pc = pctx + ((((size_t)b * 8 + h) * 8 + cc) * 16 + qq) * 16
                            + vh * 4;
            for (int j = 0; j < 4; ++j) cx[j] += pc[j] * f;
        }
        float inv = 1.f / L;
        s16x4 p;
        for (int j = 0; j < 4; ++j) p[j] = f2bf(cx[j] * inv);
        // global d = h*16 + vh*4 + j -> frag-major (d>>3)*128 + qq*8 + (d&7)
        int off = (h * 2 + (vh >> 1)) * 128 + qq * 8 + (vh & 1) * 4;
        *(s16x4*)&sctx[off] = p;
    }
    __syncthreads();
    // --- phase 2: att_out = ctx @ Wo^T; hidden = q + a1*att_out (to LDS)
    //     8 waves x 16 dcols = 128 output dims.
    {
        float a1 = alpha1[0];
        bf16x8 cA[4];
        for (int kf = 0; kf < 4; ++kf)
            cA[kf] = *(const bf16x8*)(const void*)&sctx[(kf * 4 + g) * 128 + c * 8];
        int dcol = w * 16 + c;
        f32x4 acc = {0.f, 0.f, 0.f, 0.f};
        for (int kf = 0; kf < 4; ++kf) {
            bf16x8 wB = *(const bf16x8*)(const void*)
                        (wo16 + (size_t)dcol * 128 + kf * 32 + g * 8);
            acc = mfma32(cA[kf], wB, acc);
        }
        for (int r = 0; r < 4; ++r) {
            int q = 4 * g + r;
            float hid = qin[((size_t)b * 16 + q) * 128 + dcol] + a1 * acc[r];
            shid[q * 128 + dcol] = hid;
        }
    }
    __syncthreads();
    // --- phase 3: LN2 per q-row -> shn (bf16, frag-major)
    //     512 threads: row = t>>5, 32 lanes/row, 4 elems each.
    {
        int row = t >> 5, ln = t & 31;
        float x[4], sum = 0.f, sq = 0.f;
        for (int j = 0; j < 4; ++j) {
            x[j] = shid[row * 128 + ln * 4 + j];
            sum += x[j]; sq += x[j] * x[j];
        }
        for (int o = 1; o < 32; o <<= 1) {
            sum += __shfl_xor(sum, o);
            sq  += __shfl_xor(sq, o);
        }
        float mu = sum * (1.f / 128.f);
        float var = sq * (1.f / 128.f) - mu * mu;
        float rstd = rsqrtf(var + 1e-5f);
        s16x4 hh;
        for (int j = 0; j < 4; ++j)
            hh[j] = f2bf((x[j] - mu) * rstd * g2[ln * 4 + j] + b2[ln * 4 + j]);
        // global d = ln*4 + j -> (d>>3)*128 + row*8 + (d&7)
        int off = (ln >> 1) * 128 + row * 8 + (ln & 1) * 4;
        *(s16x4*)&shn[off] = hh;
    }
    __syncthreads();
    // --- phase 4: ab = hn @ wff^T + bias; h = silu(a)*b -> shm (frag-major)
    //     8 waves x 4 nf x 16 rows = full 512 gate rows.
    {
        bf16x8 hA[4];
        for (int kf = 0; kf < 4; ++kf)
            hA[kf] = *(const bf16x8*)(const void*)&shn[(kf * 4 + g) * 128 + c * 8];
        for (int nf = 0; nf < 4; ++nf) {
            int arow = w * 64 + nf * 16 + c;
            int brow = 512 + arow;
            f32x4 aa = {0.f,0.f,0.f,0.f}, ab = {0.f,0.f,0.f,0.f};
            for (int kf = 0; kf < 4; ++kf) {
                bf16x8 wa = *(const bf16x8*)(const void*)
                            (wff16 + (size_t)arow * 128 + kf * 32 + g * 8);
                bf16x8 wb = *(const bf16x8*)(const void*)
                            (wff16 + (size_t)brow * 128 + kf * 32 + g * 8);
                aa = mfma32(hA[kf], wa, aa);
                ab = mfma32(hA[kf], wb, ab);
            }
            float ba = bff[arow], bb2 = bff[brow];
            for (int r = 0; r < 4; ++r) {
                float a = aa[r] + ba, bb = ab[r] + bb2;
                float hv = a * bb / (1.f + __expf(-a));   // silu(a)*b
                shm[(arow >> 3) * 128 + (4 * g + r) * 8 + (c & 7)] = f2bf(hv);
            }
        }
    }
    __syncthreads();
    // --- phase 5: ffout = h @ wffo^T; out = hidden + a2*(ffout + bffo)
    //     8 waves x 16 dcols.
    {
        float a2 = alpha2[0];
        int dcol = w * 16 + c;
        f32x4 acc = {0.f, 0.f, 0.f, 0.f};
        for (int kf = 0; kf < 16; ++kf) {
            bf16x8 hA = *(const bf16x8*)(const void*)
                        &shm[(kf * 4 + g) * 128 + c * 8];
            bf16x8 wB = *(const bf16x8*)(const void*)
                        (wffo16 + (size_t)dcol * 512 + kf * 32 + g * 8);
            acc = mfma32(hA, wB, acc);
        }
        float bo = bffo[dcol];
        for (int r = 0; r < 4; ++r) {
            int q = 4 * g + r;
            out[((size_t)b * 16 + q) * 128 + dcol] =
                shid[q * 128 + dcol] + a2 * (acc[r] + bo);
        }
    }
}

// ---------------------------------------------------------------------------
extern "C" void kernel_launch(void* const* d_in, const int* in_sizes, int n_in,
                              void* d_out, int out_size, void* d_ws, size_t ws_size,
                              hipStream_t stream)
{
    (void)in_sizes; (void)n_in; (void)out_size; (void)ws_size;
    const float* qin   = (const float*)d_in[0];
    const float* embed = (const float*)d_in[1];
    const unsigned char* amask = (const unsigned char*)d_in[2];
    const int*   bmask = (const int*)d_in[3];
    const float* Wkv   = (const float*)d_in[4];
    const float* Wq    = (const float*)d_in[5];
    const float* Wo    = (const float*)d_in[6];
    const float* g1    = (const float*)d_in[7];
    const float* b1    = (const float*)d_in[8];
    const float* g2    = (const float*)d_in[9];
    const float* b2    = (const float*)d_in[10];
    const float* al1   = (const float*)d_in[11];
    const float* al2   = (const float*)d_in[12];
    const float* wff   = (const float*)d_in[13];
    const float* bff   = (const float*)d_in[14];
    const float* wffo  = (const float*)d_in[15];
    const float* bffo  = (const float*)d_in[16];
    float* out = (float*)d_out;

    char* ws = (char*)d_ws;
    short* gqb    = (short*)(ws + 0);         // 256 KB bf16 gq (scaled)
    float* pml    = (float*)(ws + 262144);    // 512 KB partial (m,l)
    float* pctx   = (float*)(ws + 786432);    // 4 MB   partial ctx
    short* wkv16  = (short*)(ws + 4980736);   // 64 KB
    short* wo16   = (short*)(ws + 5046272);   // 32 KB
    short* wff16  = (short*)(ws + 5079040);   // 256 KB
    short* wffo16 = (short*)(ws + 5341184);   // 128 KB
    // total ws use: 5,472,256 bytes

    kprep<<<dim3(240),   dim3(256), 0, stream>>>(Wkv, Wo, wff, wffo,
                                                 wkv16, wo16, wff16, wffo16);
    kgq  <<<dim3(1024),  dim3(128), 0, stream>>>(qin, g1, b1, Wq, gqb);
    kattn<<<dim3(8, 64), dim3(512), 0, stream>>>(embed, bmask, amask, wkv16,
                                                 gqb, pml, pctx);
    ktail<<<dim3(64),    dim3(512), 0, stream>>>(pml, pctx, wo16, qin, al1,
                                                 g2, b2, wff16, bff, wffo16,
                                                 bffo, al2, out);
}